// Round 9
// baseline (104.523 us; speedup 1.0000x reference)
//
#include <hip/hip_runtime.h>

// Submanifold sparse 3D conv — v9: counted-vmcnt schedule (T3/T4 port).
// TR=64 rows/wave, 2-wave (128-thread) blocks, 3-slot LDS W rotation staged
// via global_load_lds (W pre-swizzled in global -> linear dest). Per phase:
//   top: vmcnt(9) [W(it+1) staged; af[it]+tab fly] ; lgkmcnt(0) ; s_barrier
//   body: ds_read fr[it+1] ; gl_lds W(it+2) ; SCHED_BARRIER ;
//         gather af[it+1] ; tab(it+3) ; 32 MFMA (fr[it], af[it]) — no waits
//
// Map identity (verified R1-R8): out[imap[m,p]] += feats[omap[m,p]] @ kernel[26-kk(m)]
// tab[27][nt][16col][4s] int (int4/lane/item); empties = N -> fb zero row.

#define CIN 64
#define COUT 64
#define TR 64
#define NOFF 26
#define NSLOT 3

typedef short bf16x8 __attribute__((ext_vector_type(8)));
typedef float f32x4 __attribute__((ext_vector_type(4)));

__device__ inline unsigned short bfbits(float f) {
    unsigned u = __builtin_bit_cast(unsigned, f);
    u += 0x7fffu + ((u >> 16) & 1u);          // RNE
    return (unsigned short)(u >> 16);
}

__device__ inline constexpr int kk_of_item(int i) {
    return (i >= 26) ? 13 : 26 - (i < 13 ? i : i + 1);
}

// ---------- prepass 1: feats f32 -> bf16 (+ zero row N) -------------------
__global__ __launch_bounds__(256) void prep_feats(const float* __restrict__ f,
                                                  unsigned short* __restrict__ fb,
                                                  int n, int next) {
    const int i8 = (blockIdx.x * 256 + threadIdx.x) * 8;
    if (i8 >= next) return;
    union { unsigned short u[8]; bf16x8 v; } r;
    if (i8 >= n) {
        r.v = (bf16x8)0;
    } else {
        const float4 v0 = *(const float4*)(f + i8);
        const float4 v1 = *(const float4*)(f + i8 + 4);
        r.u[0] = bfbits(v0.x); r.u[1] = bfbits(v0.y);
        r.u[2] = bfbits(v0.z); r.u[3] = bfbits(v0.w);
        r.u[4] = bfbits(v1.x); r.u[5] = bfbits(v1.y);
        r.u[6] = bfbits(v1.z); r.u[7] = bfbits(v1.w);
    }
    *(bf16x8*)(fb + i8) = r.v;
}

// ---------- prepass 2: W [27][c][o] f32 -> Wt [27][o][c] bf16, PRE-SWIZZLED
__global__ __launch_bounds__(256) void prep_wt(const float* __restrict__ W,
                                               unsigned short* __restrict__ Wt) {
    const int k = blockIdx.x;
    for (int idx = threadIdx.x; idx < CIN * COUT; idx += 256) {
        const int c = idx >> 6, o = idx & 63;
        const int q = c >> 3, e = c & 7;
        Wt[((k * 64 + o) * 64) + (((q ^ (o & 7)) << 3) + e)] =
            bfbits(W[(k * 64 + c) * 64 + o]);
    }
}

// ---------- prepass 3: tab init (N; identity on map 26) + scatter ---------
// layout: tab[(m*nt + tile)*64 + col*4 + s]  (int4 per lane per item)
__global__ __launch_bounds__(256) void prep_tab_init(int* __restrict__ tab,
                                                     int nt, int N) {
    const size_t i4 = ((size_t)blockIdx.x * 256 + threadIdx.x) * 4;
    const size_t total = (size_t)27 * nt * 64;
    if (i4 >= total) return;
    const size_t mstep = (size_t)nt * 64;
    int4 v; int* vp = (int*)&v;
#pragma unroll
    for (int e = 0; e < 4; ++e) {
        const size_t l = i4 + e;
        const int m = (int)(l / mstep);
        const size_t rem = l - (size_t)m * mstep;
        const int tile = (int)(rem >> 6);
        const int ee = (int)(rem & 63);
        const int row = tile * 64 + (ee & 3) * 16 + (ee >> 2);
        vp[e] = (m == 26 && row < N) ? row : N;
    }
    *(int4*)(tab + i4) = v;
}

__global__ __launch_bounds__(256) void prep_tab(const int* __restrict__ imap,
                                                const int* __restrict__ omap,
                                                int P, int nt,
                                                int* __restrict__ tab) {
    const int p = blockIdx.x * 256 + threadIdx.x;
    const int m = blockIdx.y;
    if (p >= P) return;
    const int iv = imap[(size_t)m * P + p];
    if (iv < 0) return;
    const int tile = iv >> 6, rowin = iv & 63;
    tab[((size_t)m * nt + tile) * 64 + (rowin & 15) * 4 + (rowin >> 4)] =
        omap[(size_t)m * P + p];
}

// ---------- main ----------------------------------------------------------
__global__ __launch_bounds__(128, 2) void spconv_v9(
    const unsigned short* __restrict__ fb,   // feats bf16 [N+1][64], row N = 0
    const unsigned short* __restrict__ wt,   // [27][64][64] bf16, pre-swizzled
    const int* __restrict__ tab,             // [27][nt][16][4]
    float* __restrict__ out, int N, int nt, int nwg)
{
    __shared__ unsigned short wbuf[NSLOT][4096];   // 3 x 8KB rotation

    const int tid = threadIdx.x, w = tid >> 6, lane = tid & 63;
    const int col = lane & 15, grp = lane >> 4;

    // bijective XCD swizzle (m204)
    const int orig = blockIdx.x;
    const int q = nwg >> 3, r8 = nwg & 7;
    const int xcd = orig & 7, kb = orig >> 3;
    const int sb = (xcd < r8 ? xcd * (q + 1) : r8 * (q + 1) + (xcd - r8) * q) + kb;

    const int t = sb * 2 + w;                // this wave's 64-row tile
    const int tt = (t < nt) ? t : (nt - 1);
    const int r0 = t * TR;

    // --- helpers (all static-index friendly) ---
    int4 svr[27];
    bf16x8 af[27][4][2];
    bf16x8 fr[27][8];

    auto tabload = [&](int j) {
        svr[j] = *(const int4*)(tab + ((size_t)j * nt + tt) * 64 + col * 4);
    };
    auto stage = [&](int item) {             // gl_lds: linear, wave-cooperative
        const unsigned short* wk = wt + kk_of_item(item) * 4096;
        unsigned short* dst = &wbuf[item % NSLOT][0];
#pragma unroll
        for (int qq = 0; qq < 4; ++qq) {
            const int eoff = (qq * 2 + w) * 512;         // 1KB chunks, in ushorts
            __builtin_amdgcn_global_load_lds(
                (const __attribute__((address_space(1))) void*)(wk + eoff + lane * 8),
                (__attribute__((address_space(3))) void*)(dst + eoff),
                16, 0, 0);
        }
    };
    auto read_frags = [&](int item) {        // 8 ds_read_b128, swizzled
        const unsigned short* cb = &wbuf[item % NSLOT][0];
#pragma unroll
        for (int ot = 0; ot < 4; ++ot) {
            const int o = ot * 16 + col;
            fr[item][ot * 2 + 0] = *(const bf16x8*)(cb + o * 64 + ((grp ^ (col & 7)) << 3));
            fr[item][ot * 2 + 1] = *(const bf16x8*)(cb + o * 64 + (((4 + grp) ^ (col & 7)) << 3));
        }
    };
    auto gather = [&](int item) {            // 8 x 16B from fb (row N = zeros)
        const int* sv = (const int*)&svr[item];
#pragma unroll
        for (int s = 0; s < 4; ++s) {
            const bf16x8* fp = (const bf16x8*)(fb + (size_t)sv[s] * 64 + grp * 8);
            af[item][s][0] = fp[0];
            af[item][s][1] = fp[4];
        }
    };

    f32x4 acc[4][4];
#pragma unroll
    for (int s = 0; s < 4; ++s)
#pragma unroll
        for (int ot = 0; ot < 4; ++ot) acc[s][ot] = {0.f, 0.f, 0.f, 0.f};

    // --- prologue ---
    tabload(0); tabload(1); tabload(2);
    stage(0); stage(1);
    __builtin_amdgcn_sched_barrier(0);       // pin gl_lds before gathers (vmcnt count)
    gather(0);
    asm volatile("s_waitcnt vmcnt(8)" ::: "memory");   // stages+tabs done; af[0] flies
    asm volatile("s_waitcnt lgkmcnt(0)" ::: "memory");
    __builtin_amdgcn_s_barrier();            // publish slots 0,1
    read_frags(0);

    // --- 27 fully-unrolled phases ---
#pragma unroll
    for (int it = 0; it < 27; ++it) {
        if (it > 0) {
            if (it <= 24) asm volatile("s_waitcnt vmcnt(9)" ::: "memory");
            else          asm volatile("s_waitcnt vmcnt(8)" ::: "memory");
            asm volatile("s_waitcnt lgkmcnt(0)" ::: "memory");
            __builtin_amdgcn_s_barrier();    // publishes slot (it+1)%3
        }
        if (it + 1 <= 26) read_frags(it + 1);          // issue only; await next phase
        if (it + 2 <= 26) stage(it + 2);               // into slot (it+2)%3 (drained)
        __builtin_amdgcn_sched_barrier(0);             // gl_lds strictly before gathers
        if (it + 1 <= 26) gather(it + 1);
        if (it + 3 <= 26) tabload(it + 3);

        __builtin_amdgcn_s_setprio(1);
#pragma unroll
        for (int ot = 0; ot < 4; ++ot)
#pragma unroll
            for (int s = 0; s < 4; ++s) {
                acc[s][ot] = __builtin_amdgcn_mfma_f32_16x16x32_bf16(af[it][s][0], fr[it][ot * 2 + 0], acc[s][ot], 0, 0, 0);
                acc[s][ot] = __builtin_amdgcn_mfma_f32_16x16x32_bf16(af[it][s][1], fr[it][ot * 2 + 1], acc[s][ot], 0, 0, 0);
            }
        __builtin_amdgcn_s_setprio(0);
    }

    // --- write-out ---
#pragma unroll
    for (int s = 0; s < 4; ++s)
#pragma unroll
        for (int ot = 0; ot < 4; ++ot) {
            const f32x4 cv = acc[s][ot];
#pragma unroll
            for (int reg = 0; reg < 4; ++reg) {
                const int rr = r0 + s * 16 + grp * 4 + reg;
                if (rr < N) out[(size_t)rr * 64 + ot * 16 + col] = cv[reg];
            }
        }
}

// ---------- fallback (fp32 + atomics, round-0) ----------------------------
template <int MODE>
__global__ __launch_bounds__(256) void spconv_fb(
    const float* __restrict__ feats, const float* __restrict__ W,
    const int* __restrict__ imap, const int* __restrict__ omap,
    float* __restrict__ out, int npairs)
{
    __shared__ float4 wt4[16 * 64];
    const int tid = threadIdx.x, koff = blockIdx.y;
    const float* Wk;
    const int* im = nullptr; const int* om = nullptr;
    if (MODE == 0) Wk = W + 13 * (CIN * COUT);
    else {
        const int kk = (koff < 13) ? koff : koff + 1;
        Wk = W + (size_t)kk * (CIN * COUT);
        im = imap + (size_t)koff * npairs; om = omap + (size_t)koff * npairs;
    }
    float* wts = (float*)wt4;
    for (int idx = tid; idx < CIN * COUT; idx += 256) {
        const int c = idx >> 6, o = idx & 63;
        wts[((c >> 2) * 64 + o) * 4 + (c & 3)] = Wk[idx];
    }
    __syncthreads();
    const int o = tid & 63, w = tid >> 6;
    const int base = blockIdx.x * 256 + w * 64;
    const float4* f4p = (const float4*)feats;
    for (int n = 0; n < 64; ++n) {
        const int p = base + n;
        if (p >= npairs) break;
        int i, j;
        if (MODE == 0) { i = p; j = p; }
        else { i = im[p]; if (i < 0) continue; j = om[p]; }
        i = __builtin_amdgcn_readfirstlane(i);
        float a = 0.f;
#pragma unroll
        for (int c4 = 0; c4 < 16; ++c4) {
            const float4 f = f4p[(size_t)i * 16 + c4];
            const float4 wv = wt4[c4 * 64 + o];
            a += f.x * wv.x + f.y * wv.y + f.z * wv.z + f.w * wv.w;
        }
        if (MODE == 0) out[(size_t)j * COUT + o] = a;
        else atomicAdd(&out[(size_t)j * COUT + o], a);
    }
}

extern "C" void kernel_launch(void* const* d_in, const int* in_sizes, int n_in,
                              void* d_out, int out_size, void* d_ws, size_t ws_size,
                              hipStream_t stream) {
    const float* feats = (const float*)d_in[0];
    const float* W     = (const float*)d_in[1];
    const int* imap    = (const int*)d_in[2];
    const int* omap    = (const int*)d_in[3];
    float* out         = (float*)d_out;

    const int N = in_sizes[0] / CIN;
    const int P = in_sizes[2] / NOFF;
    const int nt = (N + TR - 1) / TR;                       // 64-row tiles (3125)

    const size_t fb_bytes  = (size_t)(N + 1) * 64 * sizeof(unsigned short);
    const size_t wt_bytes  = 27 * 64 * 64 * sizeof(unsigned short);
    const size_t tab_bytes = (size_t)27 * nt * 64 * sizeof(int);

    if (ws_size < fb_bytes + wt_bytes + tab_bytes) {
        dim3 blk(256);
        dim3 gc((N + 255) / 256, 1);
        spconv_fb<0><<<gc, blk, 0, stream>>>(feats, W, nullptr, nullptr, out, N);
        dim3 go((P + 255) / 256, NOFF);
        spconv_fb<1><<<go, blk, 0, stream>>>(feats, W, imap, omap, out, P);
        return;
    }

    unsigned short* fbp = (unsigned short*)d_ws;
    unsigned short* Wt  = (unsigned short*)((char*)d_ws + fb_bytes);
    int* tab            = (int*)((char*)d_ws + fb_bytes + wt_bytes);

    const int nf = N * 64, nfe = (N + 1) * 64;
    prep_feats<<<(nfe / 8 + 255) / 256, 256, 0, stream>>>(feats, fbp, nf, nfe);
    prep_wt<<<27, 256, 0, stream>>>(W, Wt);
    const size_t tot4 = (size_t)27 * nt * 64 / 4;
    prep_tab_init<<<(int)((tot4 + 255) / 256), 256, 0, stream>>>(tab, nt, N);
    prep_tab<<<dim3((P + 255) / 256, NOFF), 256, 0, stream>>>(imap, omap, P, nt, tab);

    const int nwg = (nt + 1) / 2;                           // 1563
    spconv_v9<<<nwg, 128, 0, stream>>>(fbp, Wt, tab, out, N, nt, nwg);
}

// Round 10
// 88.210 us; speedup vs baseline: 1.1849x; 1.1849x over previous
//
#include <hip/hip_runtime.h>

// Submanifold sparse 3D conv — v10: v8 main structure (fully-unrolled 27-phase,
// reg-staged W double-buffer, lgkmcnt-only barriers) with the tab machinery
// replaced by in-kernel srctab build (rg ranges + imap/omap direct + per-wave
// LDS slot-inversion, 4-phase pipeline), and ONE fused prepass kernel.
//
// Map identity (verified R1-R9): out[imap[m,p]] += feats[omap[m,p]] @ kernel[26-kk(m)]
// rg[m][tile] = lower_bound(imap[m], tile*32)  (pads -1 -> +inf), 26 x (nt+1).
// srctab: per-wave LDS [3][32] rotation; reset=N (fb zero row), scatter omap.

#define CIN 64
#define COUT 64
#define TR 32
#define NOFF 26

typedef short bf16x8 __attribute__((ext_vector_type(8)));
typedef unsigned short ushort8 __attribute__((ext_vector_type(8)));
typedef float f32x4 __attribute__((ext_vector_type(4)));

__device__ inline unsigned short bfbits(float f) {
    unsigned u = __builtin_bit_cast(unsigned, f);
    u += 0x7fffu + ((u >> 16) & 1u);          // RNE
    return (unsigned short)(u >> 16);
}

__device__ inline constexpr int kk_of_item(int i) {
    return (i >= 26) ? 13 : 26 - (i < 13 ? i : i + 1);
}

// ---------- fused prepass: feats->bf16 (+zero row), W swizzle, rg search ---
__global__ __launch_bounds__(256) void prep_all(
    const float* __restrict__ feats, unsigned short* __restrict__ fb,
    const float* __restrict__ W, unsigned short* __restrict__ Wt,
    const int* __restrict__ imap, int* __restrict__ rg,
    int N, int P, int nt, int FB)
{
    const int bid = blockIdx.x, tid = threadIdx.x;
    if (bid < FB) {
        // feats f32 -> bf16; indices >= N*64 write zeros (zero row + pad)
        const int i8 = (bid * 256 + tid) * 8;
        const int nf = N * 64;
        if (i8 >= (N + 1) * 64) return;
        union { unsigned short u[8]; bf16x8 v; } r;
        if (i8 >= nf) {
            r.v = (bf16x8)0;
        } else {
            const float4 v0 = *(const float4*)(feats + i8);
            const float4 v1 = *(const float4*)(feats + i8 + 4);
            r.u[0] = bfbits(v0.x); r.u[1] = bfbits(v0.y);
            r.u[2] = bfbits(v0.z); r.u[3] = bfbits(v0.w);
            r.u[4] = bfbits(v1.x); r.u[5] = bfbits(v1.y);
            r.u[6] = bfbits(v1.z); r.u[7] = bfbits(v1.w);
        }
        *(bf16x8*)(fb + i8) = r.v;
    } else if (bid < FB + 27) {
        // W [27][c][o] -> Wt [27][o][c] bf16, pre-swizzled (16B unit q ^= o&7)
        const int k = bid - FB;
        for (int idx = tid; idx < CIN * COUT; idx += 256) {
            const int c = idx >> 6, o = idx & 63;
            const int q = c >> 3, e = c & 7;
            Wt[((k * 64 + o) * 64) + (((q ^ (o & 7)) << 3) + e)] =
                bfbits(W[(k * 64 + c) * 64 + o]);
        }
    } else {
        // rg[m][tile] = lower_bound(imap[m], tile*TR)
        const int idx = (bid - FB - 27) * 256 + tid;
        const int nt1 = nt + 1;
        if (idx >= NOFF * nt1) return;
        const int m = idx / nt1, tile = idx % nt1;
        const int* a = imap + (size_t)m * P;
        const int target = tile * TR;
        int lo = 0, hi = P;
        while (lo < hi) {
            const int mid = (lo + hi) >> 1;
            const int v = a[mid];
            const int key = (v < 0) ? 0x7fffffff : v;
            if (key < target) lo = mid + 1; else hi = mid;
        }
        rg[(size_t)m * nt1 + tile] = lo;
    }
}

// ---------- main ----------------------------------------------------------
__global__ __launch_bounds__(256, 4) void spconv_v10(
    const unsigned short* __restrict__ fb,   // feats bf16 [N+1][64], row N = 0
    const unsigned short* __restrict__ wt,   // [27][64][64] bf16, pre-swizzled
    const int* __restrict__ imap, const int* __restrict__ omap,
    const int* __restrict__ rg,              // [26][nt+1]
    float* __restrict__ out, int N, int P, int nt, int nwg)
{
    __shared__ unsigned short wbuf[2][4096]; // 2 x 8KB W double buffer
    __shared__ int srctab[4][3][32];         // per-wave, 3-slot rotation

    const int tid = threadIdx.x, w = tid >> 6, lane = tid & 63;
    const int col = lane & 15, grp = lane >> 4;

    // bijective XCD swizzle (m204)
    const int orig = blockIdx.x;
    const int q = nwg >> 3, r8 = nwg & 7;
    const int xcd = orig & 7, kb = orig >> 3;
    const int sb = (xcd < r8 ? xcd * (q + 1) : r8 * (q + 1) + (xcd - r8) * q) + kb;

    const int t = sb * 4 + w;                // this wave's 32-row tile
    const int tt = (t < nt) ? t : (nt - 1);
    const int r0 = t * TR;
    const int nt1 = nt + 1;

    // pipeline state — statically indexed (full unroll => rolling registers)
    int p0a[27], cnta[27];                   // rg values per item
    int mva[27];                             // packed (ov<<6)|slot per lane
    bf16x8 af[27][2][2];                     // A fragments (window ~2)
    ushort8 wr[27][2];                       // W staging regs (window ~1)

    auto RGLOAD = [&](int j) {               // 2 uniform dwords
        const int* rp = rg + (size_t)j * nt1 + tt;
        p0a[j] = rp[0];
        cnta[j] = rp[1];                     // raw p1; cnt computed at MAPS
    };
    auto MAPS = [&](int j) {                 // lanes < cnt load pair (coalesced)
        const int p0 = p0a[j];
        const int cnt = cnta[j] - p0;        // <= 32 guaranteed
        cnta[j] = cnt;
        int idx = p0 + ((lane < cnt) ? lane : 0);
        idx = (idx < P) ? idx : P - 1;
        const int iv = imap[(size_t)j * P + idx];
        const int ov = omap[(size_t)j * P + idx];
        mva[j] = (ov << 6) | ((iv - r0) & 63);
    };
    auto STWRITE = [&](int j) {              // reset then scatter (same-wave order)
        int* st = srctab[w][j % 3];
        if (lane < 32) st[lane] = N;
        if (lane < cnta[j]) st[mva[j] & 63] = mva[j] >> 6;
    };
    auto READGATHER = [&](int j) {           // srctab -> sv -> issue gathers
        int s0, s1;
        if (j < 26) {
            const int* st = srctab[w][j % 3];
            s0 = st[col];
            s1 = st[col + 16];
        } else {                             // center: identity
            const int ra = r0 + col, rb = r0 + 16 + col;
            s0 = (ra < N) ? ra : N;
            s1 = (rb < N) ? rb : N;
        }
        const bf16x8* fp = (const bf16x8*)(fb + (size_t)s0 * 64 + grp * 8);
        af[j][0][0] = fp[0];
        af[j][0][1] = fp[4];
        const bf16x8* fq = (const bf16x8*)(fb + (size_t)s1 * 64 + grp * 8);
        af[j][1][0] = fq[0];
        af[j][1][1] = fq[4];
    };

    // --- prologue ---
#pragma unroll
    for (int j = 0; j < 4; ++j) if (j < 26) RGLOAD(j);
#pragma unroll
    for (int j = 0; j < 3; ++j) if (j < 26) MAPS(j);
    STWRITE(0); STWRITE(1);

    {   // W0 -> buf0 via temp regs; W1 -> wr[1]
        const unsigned short* wk0 = wt + kk_of_item(0) * 4096;
        const ushort8 t0 = *(const ushort8*)(wk0 + tid * 8);
        const ushort8 t1 = *(const ushort8*)(wk0 + 2048 + tid * 8);
        const unsigned short* wk1 = wt + kk_of_item(1) * 4096;
        wr[1][0] = *(const ushort8*)(wk1 + tid * 8);
        wr[1][1] = *(const ushort8*)(wk1 + 2048 + tid * 8);
        *(ushort8*)(&wbuf[0][tid * 8]) = t0;
        *(ushort8*)(&wbuf[0][2048 + tid * 8]) = t1;
    }
    READGATHER(0);
    asm volatile("s_waitcnt lgkmcnt(0)" ::: "memory");
    __builtin_amdgcn_s_barrier();

    f32x4 acc[2][4];
#pragma unroll
    for (int s = 0; s < 2; ++s)
#pragma unroll
        for (int ot = 0; ot < 4; ++ot) acc[s][ot] = {0.f, 0.f, 0.f, 0.f};

    // --- 27 fully-unrolled phases ---
#pragma unroll
    for (int it = 0; it < 27; ++it) {
        if (it + 4 < 26) RGLOAD(it + 4);
        if (it + 3 < 26) MAPS(it + 3);
        if (it + 2 < 26) STWRITE(it + 2);
        if (it + 1 <= 26) READGATHER(it + 1);
        // W pipeline: load (it+2) -> regs; ds_write (it+1) from last phase's regs
        if (it + 2 <= 26) {
            const unsigned short* wk = wt + kk_of_item(it + 2) * 4096;
            wr[it + 2][0] = *(const ushort8*)(wk + tid * 8);
            wr[it + 2][1] = *(const ushort8*)(wk + 2048 + tid * 8);
        }
        if (it + 1 <= 26) {
            unsigned short* nb = wbuf[(it + 1) & 1];
            *(ushort8*)(&nb[tid * 8]) = wr[it + 1][0];
            *(ushort8*)(&nb[2048 + tid * 8]) = wr[it + 1][1];
        }
        // compute item it: 8 swizzled ds_read_b128 + 16 MFMA
        const unsigned short* cb = wbuf[it & 1];
        __builtin_amdgcn_s_setprio(1);
#pragma unroll
        for (int ot = 0; ot < 4; ++ot) {
            const int o = ot * 16 + col;
            const bf16x8 b0 = *(const bf16x8*)(cb + o * 64 + ((grp ^ (col & 7)) << 3));
            const bf16x8 b1 = *(const bf16x8*)(cb + o * 64 + (((4 + grp) ^ (col & 7)) << 3));
#pragma unroll
            for (int s = 0; s < 2; ++s) {
                acc[s][ot] = __builtin_amdgcn_mfma_f32_16x16x32_bf16(af[it][s][0], b0, acc[s][ot], 0, 0, 0);
                acc[s][ot] = __builtin_amdgcn_mfma_f32_16x16x32_bf16(af[it][s][1], b1, acc[s][ot], 0, 0, 0);
            }
        }
        __builtin_amdgcn_s_setprio(0);
        if (it < 26) {
            asm volatile("s_waitcnt lgkmcnt(0)" ::: "memory");
            __builtin_amdgcn_s_barrier();
        }
    }

    // --- write-out ---
#pragma unroll
    for (int s = 0; s < 2; ++s)
#pragma unroll
        for (int ot = 0; ot < 4; ++ot) {
            const f32x4 cv = acc[s][ot];
#pragma unroll
            for (int reg = 0; reg < 4; ++reg) {
                const int rr = r0 + s * 16 + grp * 4 + reg;
                if (rr < N) out[(size_t)rr * 64 + ot * 16 + col] = cv[reg];
            }
        }
}

// ---------- fallback (fp32 + atomics, round-0) ----------------------------
template <int MODE>
__global__ __launch_bounds__(256) void spconv_fb(
    const float* __restrict__ feats, const float* __restrict__ W,
    const int* __restrict__ imap, const int* __restrict__ omap,
    float* __restrict__ out, int npairs)
{
    __shared__ float4 wt4[16 * 64];
    const int tid = threadIdx.x, koff = blockIdx.y;
    const float* Wk;
    const int* im = nullptr; const int* om = nullptr;
    if (MODE == 0) Wk = W + 13 * (CIN * COUT);
    else {
        const int kk = (koff < 13) ? koff : koff + 1;
        Wk = W + (size_t)kk * (CIN * COUT);
        im = imap + (size_t)koff * npairs; om = omap + (size_t)koff * npairs;
    }
    float* wts = (float*)wt4;
    for (int idx = tid; idx < CIN * COUT; idx += 256) {
        const int c = idx >> 6, o = idx & 63;
        wts[((c >> 2) * 64 + o) * 4 + (c & 3)] = Wk[idx];
    }
    __syncthreads();
    const int o = tid & 63, w = tid >> 6;
    const int base = blockIdx.x * 256 + w * 64;
    const float4* f4p = (const float4*)feats;
    for (int n = 0; n < 64; ++n) {
        const int p = base + n;
        if (p >= npairs) break;
        int i, j;
        if (MODE == 0) { i = p; j = p; }
        else { i = im[p]; if (i < 0) continue; j = om[p]; }
        i = __builtin_amdgcn_readfirstlane(i);
        float a = 0.f;
#pragma unroll
        for (int c4 = 0; c4 < 16; ++c4) {
            const float4 f = f4p[(size_t)i * 16 + c4];
            const float4 wv = wt4[c4 * 64 + o];
            a += f.x * wv.x + f.y * wv.y + f.z * wv.z + f.w * wv.w;
        }
        if (MODE == 0) out[(size_t)j * COUT + o] = a;
        else atomicAdd(&out[(size_t)j * COUT + o], a);
    }
}

extern "C" void kernel_launch(void* const* d_in, const int* in_sizes, int n_in,
                              void* d_out, int out_size, void* d_ws, size_t ws_size,
                              hipStream_t stream) {
    const float* feats = (const float*)d_in[0];
    const float* W     = (const float*)d_in[1];
    const int* imap    = (const int*)d_in[2];
    const int* omap    = (const int*)d_in[3];
    float* out         = (float*)d_out;

    const int N = in_sizes[0] / CIN;
    const int P = in_sizes[2] / NOFF;
    const int nt = (N + TR - 1) / TR;                       // 6250
    const int nt1 = nt + 1;

    const size_t fb_bytes = (size_t)(N + 1) * 64 * sizeof(unsigned short);
    const size_t wt_bytes = 27 * 64 * 64 * sizeof(unsigned short);
    const size_t rg_bytes = (size_t)NOFF * nt1 * sizeof(int);

    if (ws_size < fb_bytes + wt_bytes + rg_bytes) {
        dim3 blk(256);
        dim3 gc((N + 255) / 256, 1);
        spconv_fb<0><<<gc, blk, 0, stream>>>(feats, W, nullptr, nullptr, out, N);
        dim3 go((P + 255) / 256, NOFF);
        spconv_fb<1><<<go, blk, 0, stream>>>(feats, W, imap, omap, out, P);
        return;
    }

    unsigned short* fbp = (unsigned short*)d_ws;
    unsigned short* Wt  = (unsigned short*)((char*)d_ws + fb_bytes);
    int* rg             = (int*)((char*)d_ws + fb_bytes + wt_bytes);

    // one fused prepass launch
    const int FB  = ((N + 1) * 64 + 2047) / 2048;           // feats blocks
    const int RGB = (NOFF * nt1 + 255) / 256;               // rg blocks
    prep_all<<<FB + 27 + RGB, 256, 0, stream>>>(feats, fbp, W, Wt, imap, rg,
                                                N, P, nt, FB);

    const int nwg = (nt + 3) / 4;                           // 1563
    spconv_v10<<<nwg, 256, 0, stream>>>(fbp, Wt, imap, omap, rg, out,
                                        N, P, nt, nwg);
}